// Round 8
// baseline (841.166 us; speedup 1.0000x reference)
//
#include <hip/hip_runtime.h>

// GRU, T=4096, B=256, I=2, H=32, O=1.
// Only batch row 255 reaches the output -> compute only that row.
// Single-wave sequential recurrence; CHAIN-bound (R3==R7==420 cyc/step
// despite 2x issue difference -> dependency chain, and the ds_bpermute
// z-exchange (~110 cyc DS latency, m117) is the biggest single link).
// R8: no cross-half exchange at all -- every lane computes r,z,n for its own
//     column j (3 fp16 dot2 chains, 48 weight VGPRs). Pack simplified:
//     only even lanes are readlane sources, so no order-fixing cndmasks.

#define TT 4096

typedef _Float16 h2 __attribute__((ext_vector_type(2)));

__device__ __forceinline__ float rl(float v, int l) {
    return __int_as_float(__builtin_amdgcn_readlane(__float_as_int(v), l));
}
__device__ __forceinline__ int rli(int v, int l) {
    return __builtin_amdgcn_readlane(v, l);
}
__device__ __forceinline__ float fexp2(float x) { return __builtin_amdgcn_exp2f(x); }
__device__ __forceinline__ float frcp(float x)  { return __builtin_amdgcn_rcpf(x); }
__device__ __forceinline__ h2 asph(int v) { return __builtin_bit_cast(h2, v); }

#define NLOG2E  (-1.44269504088896340736f)   // r/z pre-activations pre-scaled
#define TLOG2E  ( 2.88539008177792681472f)   // n pre-activation pre-scaled

// One wave. Lane l computes gates r,z,n for column j = l&31 (upper half
// duplicates lower half -- same rows, same data, benign dup stores).
// h broadcast as 16 packed fp16 pairs via readlane from even lanes.
__global__ __launch_bounds__(64, 1)
__attribute__((amdgpu_waves_per_eu(1)))
void gru_seq(const float* __restrict__ x,
             const float* __restrict__ w_ih,
             const float* __restrict__ w_hh,
             const float* __restrict__ b_ih,
             const float* __restrict__ b_hh,
             float* __restrict__ hbuf)
{
    const int lane = threadIdx.x;
    const int low  = lane & 31;
    const int row_r = low;        // r row
    const int row_z = 32 + low;   // z row
    const int row_n = 64 + low;   // n row

    // fp16 weights, exp2 scales folded: 3 x 16 VGPRs.
    h2 wr[16], wz[16], wn[16];
#pragma unroll
    for (int m = 0; m < 16; ++m) {
        wr[m] = h2{(_Float16)(w_hh[row_r * 32 + 2 * m]     * NLOG2E),
                   (_Float16)(w_hh[row_r * 32 + 2 * m + 1] * NLOG2E)};
        wz[m] = h2{(_Float16)(w_hh[row_z * 32 + 2 * m]     * NLOG2E),
                   (_Float16)(w_hh[row_z * 32 + 2 * m + 1] * NLOG2E)};
        wn[m] = h2{(_Float16)(w_hh[row_n * 32 + 2 * m]     * TLOG2E),
                   (_Float16)(w_hh[row_n * 32 + 2 * m + 1] * TLOG2E)};
    }

    const float wir0 = w_ih[row_r * 2 + 0] * NLOG2E;
    const float wir1 = w_ih[row_r * 2 + 1] * NLOG2E;
    const float wiz0 = w_ih[row_z * 2 + 0] * NLOG2E;
    const float wiz1 = w_ih[row_z * 2 + 1] * NLOG2E;
    const float win0 = w_ih[row_n * 2 + 0] * TLOG2E;
    const float win1 = w_ih[row_n * 2 + 1] * TLOG2E;
    const float br = (b_ih[row_r] + b_hh[row_r]) * NLOG2E;  // r: both biases
    const float bz = (b_ih[row_z] + b_hh[row_z]) * NLOG2E;  // z: both biases
    const float bin = b_ih[row_n] * TLOG2E;                 // n: outside r*(...)
    const float bhn = b_hh[row_n] * TLOG2E;                 // n: inside r*(...)

    float h_el = 0.0f;            // lane's copy of h[low], fp32
    int hsp[16];                  // wave-uniform packed fp16 h pairs (SGPRs)
#pragma unroll
    for (int m = 0; m < 16; ++m) hsp[m] = 0;

    // x[t, 255, 0:2] as float2 at index t*256+255; 64 steps per lane-load,
    // prefetched one block ahead.
    const float2* xp = (const float2*)x;
    float2 xv = xp[(size_t)lane * 256 + 255];

    for (int tb = 0; tb < 64; ++tb) {
        float2 xv_next = xv;
        if (tb < 63) xv_next = xp[((size_t)(tb + 1) * 64 + lane) * 256 + 255];
        // transposed layout: hbuf[j*TT + t], t = tb*64 + i
        float* hout = hbuf + (size_t)low * TT + tb * 64;

#pragma unroll 4
        for (int i = 0; i < 64; ++i) {
            const float x0 = rl(xv.x, i);          // uniform lane idx i
            const float x1 = rl(xv.y, i);
            const float base_r = fmaf(x1, wir1, fmaf(x0, wir0, br));
            const float base_z = fmaf(x1, wiz1, fmaf(x0, wiz0, bz));
            const float xn     = fmaf(x1, win1, fmaf(x0, win0, bin));

            // 3 gate dots via v_dot2_f32_f16, 2 accumulator chains each
            float r0 = base_r, r1 = 0.f;
            float z0 = base_z, z1 = 0.f;
            float n0 = bhn,    n1 = 0.f;
#pragma unroll
            for (int m = 0; m < 16; m += 2) {
                const h2 hA = asph(hsp[m]);
                const h2 hB = asph(hsp[m + 1]);
                r0 = __builtin_amdgcn_fdot2(wr[m],     hA, r0, false);
                r1 = __builtin_amdgcn_fdot2(wr[m + 1], hB, r1, false);
                z0 = __builtin_amdgcn_fdot2(wz[m],     hA, z0, false);
                z1 = __builtin_amdgcn_fdot2(wz[m + 1], hB, z1, false);
                n0 = __builtin_amdgcn_fdot2(wn[m],     hA, n0, false);
                n1 = __builtin_amdgcn_fdot2(wn[m + 1], hB, n1, false);
            }
            const float pre_r = r0 + r1;           // -log2e * (r pre-act)
            const float pre_z = z0 + z1;           // -log2e * (z pre-act)
            const float hn_s  = n0 + n1;           // 2log2e * (b_hh + h.w_n)

            const float rv = frcp(1.0f + fexp2(pre_r));   // sigmoid(r)
            const float zv = frcp(1.0f + fexp2(pre_z));   // sigmoid(z), || path
            // n = tanh(xn + r*hn), arg pre-scaled by 2log2e
            const float nv = fmaf(-2.0f, frcp(1.0f + fexp2(fmaf(rv, hn_s, xn))), 1.0f);
            h_el = fmaf(zv, h_el - nv, nv);        // h = n + z*(h-n)

            hout[i] = h_el;   // off-chain store; both halves same addr+data

            // pack pair (h[2m], h[2m+1]) -- valid on EVEN lanes (the only
            // readlane sources), odd-lane garbage never read.
            const float nb = __int_as_float(__builtin_amdgcn_update_dpp(
                0, __float_as_int(h_el), 0xB1, 0xF, 0xF, true));  // lane^1
            const int pk = __builtin_bit_cast(int, __builtin_amdgcn_cvt_pkrtz(h_el, nb));
#pragma unroll
            for (int m = 0; m < 16; ++m) hsp[m] = rli(pk, 2 * m);
        }
        xv = xv_next;
    }
}

// out[t] = sum_j hbuf[j*TT + t] * w_fc[j] + b_fc   (transposed hbuf)
__global__ void fc_out(const float* __restrict__ hbuf,
                       const float* __restrict__ w_fc,
                       const float* __restrict__ b_fc,
                       float* __restrict__ out)
{
    const int t = blockIdx.x * blockDim.x + threadIdx.x;
    if (t >= TT) return;
    float acc = 0.f;
#pragma unroll
    for (int j = 0; j < 32; ++j) acc = fmaf(hbuf[j * TT + t], w_fc[j], acc);
    out[t] = acc + b_fc[0];
}

extern "C" void kernel_launch(void* const* d_in, const int* in_sizes, int n_in,
                              void* d_out, int out_size, void* d_ws, size_t ws_size,
                              hipStream_t stream) {
    const float* x    = (const float*)d_in[0];
    const float* w_ih = (const float*)d_in[1];
    const float* w_hh = (const float*)d_in[2];
    const float* b_ih = (const float*)d_in[3];
    const float* b_hh = (const float*)d_in[4];
    const float* w_fc = (const float*)d_in[5];
    const float* b_fc = (const float*)d_in[6];
    float* out  = (float*)d_out;
    float* hbuf = (float*)d_ws;   // 32*TT*4 = 512 KB

    gru_seq<<<1, 64, 0, stream>>>(x, w_ih, w_hh, b_ih, b_hh, hbuf);
    fc_out<<<TT / 256, 256, 0, stream>>>(hbuf, w_fc, b_fc, out);
}